// Round 6
// baseline (180.657 us; speedup 1.0000x reference)
//
#include <hip/hip_runtime.h>

// Problem dims (hard-coded in reference)
#define DD   768
#define NN   512
#define MM   512

#define PRE_K 2.88539008177792681472f   // 2*log2(e)

typedef __attribute__((ext_vector_type(8))) short bf8;    // 8 bf16 (4 VGPRs)
typedef __attribute__((ext_vector_type(4))) float f32x4;  // MFMA C/D

__device__ __forceinline__ float fexp(float x) { return __builtin_amdgcn_exp2f(x); }
__device__ __forceinline__ float frcp(float x) { return __builtin_amdgcn_rcpf(x); }
__device__ __forceinline__ float fast_tanh(float x) {
  return 1.0f - 2.0f * frcp(fexp(PRE_K * x) + 1.0f);
}

// fp32 -> bf16 (RNE) and back
__device__ __forceinline__ unsigned short f2bf(float x) {
  unsigned u = __builtin_bit_cast(unsigned, x);
  u += 0x7FFFu + ((u >> 16) & 1u);
  return (unsigned short)(u >> 16);
}
__device__ __forceinline__ float bf2f(unsigned short h) {
  unsigned u = ((unsigned)h) << 16;
  return __builtin_bit_cast(float, u);
}
__device__ __forceinline__ void split2(float x, unsigned short& h, unsigned short& l) {
  h = f2bf(x);
  l = f2bf(x - bf2f(h));
}

// ---- prep A: elementwise hi/lo split of text, visual, W3 (layout [row][k]) -
__global__ __launch_bounds__(256) void convert_kernel(
    const float* __restrict__ text, const float* __restrict__ visual,
    const float* __restrict__ W3,
    ushort* __restrict__ th, ushort* __restrict__ tl,
    ushort* __restrict__ vh, ushort* __restrict__ vl,
    ushort* __restrict__ w3h, ushort* __restrict__ w3l)
{
  const int z = blockIdx.z;
  const float* src = (z == 0) ? text : (z == 1) ? visual : W3;
  ushort* dh = (z == 0) ? th : (z == 1) ? vh : w3h;
  ushort* dl = (z == 0) ? tl : (z == 1) ? vl : w3l;
  const int count = ((z == 2) ? DD * DD : NN * DD) / 4;
  const int i = blockIdx.x * 256 + threadIdx.x;
  if (i >= count) return;
  const float4 v = *(const float4*)&src[(size_t)i * 4];
  ushort4 h, l;
  split2(v.x, h.x, l.x); split2(v.y, h.y, l.y);
  split2(v.z, h.z, l.z); split2(v.w, h.w, l.w);
  *(ushort4*)&dh[(size_t)i * 4] = h;
  *(ushort4*)&dl[(size_t)i * 4] = l;
}

// ---- prep B: transpose + split W1, W2 -> [j][k] hi/lo -----------------------
__global__ __launch_bounds__(256) void transpose_kernel(
    const float* __restrict__ W1, const float* __restrict__ W2,
    ushort* __restrict__ w1th, ushort* __restrict__ w1tl,
    ushort* __restrict__ w2th, ushort* __restrict__ w2tl)
{
  __shared__ float Lt[32][33];
  const float* W = blockIdx.z ? W2 : W1;
  ushort* oh = blockIdx.z ? w2th : w1th;
  ushort* ol = blockIdx.z ? w2tl : w1tl;
  const int k0 = blockIdx.y * 32, j0 = blockIdx.x * 32;
  const int t = threadIdx.x;
  {
    const int k = t >> 3, j4 = (t & 7) * 4;
    const float4 v = *(const float4*)&W[(size_t)(k0 + k) * DD + j0 + j4];
    Lt[j4 + 0][k] = v.x; Lt[j4 + 1][k] = v.y;
    Lt[j4 + 2][k] = v.z; Lt[j4 + 3][k] = v.w;
  }
  __syncthreads();
  {
    const int j = t >> 3, k4 = (t & 7) * 4;
    ushort4 h, l;
    split2(Lt[j][k4 + 0], h.x, l.x); split2(Lt[j][k4 + 1], h.y, l.y);
    split2(Lt[j][k4 + 2], h.z, l.z); split2(Lt[j][k4 + 3], h.w, l.w);
    *(ushort4*)&oh[(size_t)(j0 + j) * DD + k0 + k4] = h;
    *(ushort4*)&ol[(size_t)(j0 + j) * DD + k0 + k4] = l;
  }
}

// ---- MFMA GEMM 1: z=0: A=text@W1 -> Ah/Al(bf16) ; z=1: kw2t=PRE_K*text@W2 ;
// z=2: kw3v=PRE_K*visual@W3^T.  Split-bf16: hi*hi + hi*lo + lo*hi.
// 64x64 out tile, 4 waves (wave w = rows 16w..16w+15, 4 col-tiles of 16).
// Frags straight from global (no LDS): A by m=lane&15,k=quad*8; B by n=lane&15.
__global__ __launch_bounds__(256) void mfma1_kernel(
    const ushort* __restrict__ th, const ushort* __restrict__ tl,
    const ushort* __restrict__ vh, const ushort* __restrict__ vl,
    const ushort* __restrict__ w1th, const ushort* __restrict__ w1tl,
    const ushort* __restrict__ w2th, const ushort* __restrict__ w2tl,
    const ushort* __restrict__ w3h, const ushort* __restrict__ w3l,
    ushort* __restrict__ Ah, ushort* __restrict__ Al,
    float* __restrict__ kw2t, float* __restrict__ kw3v)
{
  const int z = blockIdx.z;
  const int i0 = blockIdx.y * 64;   // out rows (512)
  const int j0 = blockIdx.x * 64;   // out cols (768)
  const ushort *Arh, *Arl, *Brh, *Brl;
  if (z == 0)      { Arh = th; Arl = tl; Brh = w1th; Brl = w1tl; }
  else if (z == 1) { Arh = th; Arl = tl; Brh = w2th; Brl = w2tl; }
  else             { Arh = vh; Arl = vl; Brh = w3h;  Brl = w3l;  }

  const int lane = threadIdx.x & 63;
  const int wave = threadIdx.x >> 6;
  const int r15  = lane & 15;
  const int quad = lane >> 4;

  const ushort* aph = Arh + (size_t)(i0 + 16 * wave + r15) * DD + quad * 8;
  const ushort* apl = Arl + (size_t)(i0 + 16 * wave + r15) * DD + quad * 8;
  const ushort* bph = Brh + (size_t)(j0 + r15) * DD + quad * 8;
  const ushort* bpl = Brl + (size_t)(j0 + r15) * DD + quad * 8;

  f32x4 acc[4];
  #pragma unroll
  for (int c = 0; c < 4; ++c) acc[c] = (f32x4){0.f, 0.f, 0.f, 0.f};

  for (int ks = 0; ks < DD; ks += 32) {
    const bf8 a_h = *(const bf8*)(aph + ks);
    const bf8 a_l = *(const bf8*)(apl + ks);
    #pragma unroll
    for (int c = 0; c < 4; ++c) {
      const bf8 b_h = *(const bf8*)(bph + (size_t)c * 16 * DD + ks);
      const bf8 b_l = *(const bf8*)(bpl + (size_t)c * 16 * DD + ks);
      acc[c] = __builtin_amdgcn_mfma_f32_16x16x32_bf16(a_h, b_h, acc[c], 0, 0, 0);
      acc[c] = __builtin_amdgcn_mfma_f32_16x16x32_bf16(a_h, b_l, acc[c], 0, 0, 0);
      acc[c] = __builtin_amdgcn_mfma_f32_16x16x32_bf16(a_l, b_h, acc[c], 0, 0, 0);
    }
  }

  // epilogue: C/D layout col=lane&15, row=quad*4+reg
  if (z == 0) {
    #pragma unroll
    for (int c = 0; c < 4; ++c)
      #pragma unroll
      for (int r = 0; r < 4; ++r) {
        const size_t o = (size_t)(i0 + 16 * wave + quad * 4 + r) * DD + j0 + 16 * c + r15;
        unsigned short h, l;
        split2(acc[c][r], h, l);
        Ah[o] = h; Al[o] = l;
      }
  } else {
    float* Out = (z == 1) ? kw2t : kw3v;
    #pragma unroll
    for (int c = 0; c < 4; ++c)
      #pragma unroll
      for (int r = 0; r < 4; ++r)
        Out[(size_t)(i0 + 16 * wave + quad * 4 + r) * DD + j0 + 16 * c + r15] =
            acc[c][r] * PRE_K;
  }
}

// ---- MFMA GEMM 2: Q[z] = A @ visual^T over K range z*192..+192 -------------
// out 512x512, 64x64 tiles, K-split 4 -> 256 blocks. fp32 partials.
__global__ __launch_bounds__(256) void mfma2_kernel(
    const ushort* __restrict__ Ah, const ushort* __restrict__ Al,
    const ushort* __restrict__ vh, const ushort* __restrict__ vl,
    float* __restrict__ Q)
{
  const int z  = blockIdx.z;
  const int k0 = z * (DD / 4);
  const int i0 = blockIdx.y * 64;
  const int j0 = blockIdx.x * 64;

  const int lane = threadIdx.x & 63;
  const int wave = threadIdx.x >> 6;
  const int r15  = lane & 15;
  const int quad = lane >> 4;

  const ushort* aph = Ah + (size_t)(i0 + 16 * wave + r15) * DD + k0 + quad * 8;
  const ushort* apl = Al + (size_t)(i0 + 16 * wave + r15) * DD + k0 + quad * 8;
  const ushort* bph = vh + (size_t)(j0 + r15) * DD + k0 + quad * 8;
  const ushort* bpl = vl + (size_t)(j0 + r15) * DD + k0 + quad * 8;

  f32x4 acc[4];
  #pragma unroll
  for (int c = 0; c < 4; ++c) acc[c] = (f32x4){0.f, 0.f, 0.f, 0.f};

  for (int ks = 0; ks < DD / 4; ks += 32) {
    const bf8 a_h = *(const bf8*)(aph + ks);
    const bf8 a_l = *(const bf8*)(apl + ks);
    #pragma unroll
    for (int c = 0; c < 4; ++c) {
      const bf8 b_h = *(const bf8*)(bph + (size_t)c * 16 * DD + ks);
      const bf8 b_l = *(const bf8*)(bpl + (size_t)c * 16 * DD + ks);
      acc[c] = __builtin_amdgcn_mfma_f32_16x16x32_bf16(a_h, b_h, acc[c], 0, 0, 0);
      acc[c] = __builtin_amdgcn_mfma_f32_16x16x32_bf16(a_h, b_l, acc[c], 0, 0, 0);
      acc[c] = __builtin_amdgcn_mfma_f32_16x16x32_bf16(a_l, b_h, acc[c], 0, 0, 0);
    }
  }

  float* Out = Q + (size_t)z * NN * MM;
  #pragma unroll
  for (int c = 0; c < 4; ++c)
    #pragma unroll
    for (int r = 0; r < 4; ++r)
      Out[(size_t)(i0 + 16 * wave + quad * 4 + r) * MM + j0 + 16 * c + r15] = acc[c][r];
}

// T[n] = sum_d text[n,d]
__global__ __launch_bounds__(64) void tsum_kernel(
    const float* __restrict__ text, float* __restrict__ T)
{
  const int n = blockIdx.x;
  const int lane = threadIdx.x;
  float s = 0.f;
  #pragma unroll
  for (int i = 0; i < DD / 64; ++i) s += text[n * DD + lane + i * 64];
  #pragma unroll
  for (int off = 32; off; off >>= 1) s += __shfl_down(s, off);
  if (lane == 0) T[n] = s;
}

// ---- main fused kernel (unchanged from R5) ---------------------------------
#define DCH    64
#define DRANGE 384
#define MLDW   68

__global__ __launch_bounds__(256) void main_kernel(
    const float* __restrict__ text, const float* __restrict__ kw2t,
    const float* __restrict__ kw3v, const float* __restrict__ Q,
    float* __restrict__ Spart)
{
  __shared__ float ts[16][MLDW];
  __shared__ float w2s[16][MLDW];
  __shared__ float w3s[32][MLDW];

  const int tid = threadIdx.x;
  const int nl = tid >> 4;
  const int ml = tid & 15;
  const int n0 = blockIdx.y * 16;
  const int m0 = blockIdx.x * 32;
  const int z  = blockIdx.z;
  const int n  = n0 + nl;
  const int mA = m0 + ml, mB = mA + 16;
  const int dbase = z * DRANGE;

  float cA = 0.f, cB = 0.f;
  #pragma unroll
  for (int zz = 0; zz < 4; ++zz) {
    const float* q = Q + (size_t)zz * NN * MM + (size_t)n * MM;
    cA += q[mA]; cB += q[mB];
  }
  cA = fast_tanh(cA); cB = fast_tanh(cB);

  float4 aA = {0.f, 0.f, 0.f, 0.f};
  float4 aB = {0.f, 0.f, 0.f, 0.f};

  const int srow = tid >> 4;
  const int sc4  = (tid & 15) << 2;

  for (int dc = 0; dc < DRANGE; dc += DCH) {
    const int d0 = dbase + dc;
    *(float4*)&ts[srow][sc4]       = *(const float4*)&text[(size_t)(n0 + srow) * DD + d0 + sc4];
    *(float4*)&w2s[srow][sc4]      = *(const float4*)&kw2t[(size_t)(n0 + srow) * DD + d0 + sc4];
    *(float4*)&w3s[srow][sc4]      = *(const float4*)&kw3v[(size_t)(m0 + srow) * DD + d0 + sc4];
    *(float4*)&w3s[srow + 16][sc4] = *(const float4*)&kw3v[(size_t)(m0 + 16 + srow) * DD + d0 + sc4];
    __syncthreads();

    #pragma unroll 4
    for (int j = 0; j < DCH; j += 4) {
      const float4 tv  = *(const float4*)&ts[nl][j];
      const float4 w2  = *(const float4*)&w2s[nl][j];
      const float4 w3A = *(const float4*)&w3s[ml][j];
      const float4 w3B = *(const float4*)&w3s[ml + 16][j];
      aA.x = fmaf(tv.x, frcp(fexp(fmaf(w3A.x, cA, w2.x)) + 1.0f), aA.x);
      aA.y = fmaf(tv.y, frcp(fexp(fmaf(w3A.y, cA, w2.y)) + 1.0f), aA.y);
      aA.z = fmaf(tv.z, frcp(fexp(fmaf(w3A.z, cA, w2.z)) + 1.0f), aA.z);
      aA.w = fmaf(tv.w, frcp(fexp(fmaf(w3A.w, cA, w2.w)) + 1.0f), aA.w);
      aB.x = fmaf(tv.x, frcp(fexp(fmaf(w3B.x, cB, w2.x)) + 1.0f), aB.x);
      aB.y = fmaf(tv.y, frcp(fexp(fmaf(w3B.y, cB, w2.y)) + 1.0f), aB.y);
      aB.z = fmaf(tv.z, frcp(fexp(fmaf(w3B.z, cB, w2.z)) + 1.0f), aB.z);
      aB.w = fmaf(tv.w, frcp(fexp(fmaf(w3B.w, cB, w2.w)) + 1.0f), aB.w);
    }
    __syncthreads();
  }

  float* Sp = Spart + (size_t)z * NN * MM + (size_t)n * MM;
  Sp[mA] = (aA.x + aA.y) + (aA.z + aA.w);
  Sp[mB] = (aB.x + aB.y) + (aB.z + aB.w);
}

// out[n,m] = T[n] - 2*(Spart0 + Spart1)
__global__ __launch_bounds__(256) void combine_kernel(
    const float* __restrict__ Spart, const float* __restrict__ T,
    float* __restrict__ out)
{
  const size_t i = ((size_t)blockIdx.x * 256 + threadIdx.x) * 4;
  const int n = (int)(i >> 9);
  const float Tn = T[n];
  const float4 s0 = *(const float4*)&Spart[i];
  const float4 s1 = *(const float4*)&Spart[(size_t)NN * MM + i];
  float4 o;
  o.x = Tn - 2.0f * (s0.x + s1.x);
  o.y = Tn - 2.0f * (s0.y + s1.y);
  o.z = Tn - 2.0f * (s0.z + s1.z);
  o.w = Tn - 2.0f * (s0.w + s1.w);
  *(float4*)&out[i] = o;
}

// ---- launcher --------------------------------------------------------------
extern "C" void kernel_launch(void* const* d_in, const int* in_sizes, int n_in,
                              void* d_out, int out_size, void* d_ws, size_t ws_size,
                              hipStream_t stream) {
  const float* text   = (const float*)d_in[0];
  const float* visual = (const float*)d_in[1];
  const float* W1     = (const float*)d_in[2];
  const float* W2     = (const float*)d_in[3];
  const float* W3     = (const float*)d_in[4];
  float* out = (float*)d_out;

  // Byte-offset workspace layout (total ~14.25 MB, <= 14.7 MB proven in R3):
  //   th/tl, vh/vl: bf16 hi/lo of text, visual       (4 x 768 KB)
  //   w1t,w2t h/l : bf16 hi/lo of W1^T, W2^T [j][k]  (4 x 1.125 MB)
  //   w3 h/l      : bf16 hi/lo of W3 [d][k]          (2 x 1.125 MB)
  //   Ah/Al       : bf16 hi/lo of A=text@W1          (2 x 768 KB)
  //   kw2t/kw3v   : fp32                              (2 x 1.5 MB)
  //   T           : fp32[512]
  // Reuse (serial stream order makes these safe):
  //   Spart (2 MB)  -> over w1t h/l  (dead after mfma1)
  //   Q     (4 MB)  -> over w2t h/l + w3 h/l (dead after mfma1)
  char* base = (char*)d_ws;
  ushort* th   = (ushort*)(base);                 // 786432 B each
  ushort* tl   = (ushort*)(base + 786432);
  ushort* vh   = (ushort*)(base + 1572864);
  ushort* vl   = (ushort*)(base + 2359296);
  ushort* w1th = (ushort*)(base + 3145728);       // 1179648 B each
  ushort* w1tl = (ushort*)(base + 4325376);
  ushort* w2th = (ushort*)(base + 5505024);
  ushort* w2tl = (ushort*)(base + 6684672);
  ushort* w3h  = (ushort*)(base + 7864320);
  ushort* w3l  = (ushort*)(base + 9043968);
  ushort* Ah   = (ushort*)(base + 10223616);      // 786432 B each
  ushort* Al   = (ushort*)(base + 11010048);
  float*  kw2t = (float*) (base + 11796480);      // 1572864 B each
  float*  kw3v = (float*) (base + 13369344);
  float*  T    = (float*) (base + 14942208);      // 2048 B
  float*  Spart = (float*)(base + 3145728);       // reuse w1t (2097152 B fits)
  float*  Q     = (float*)(base + 5505024);       // reuse w2t+w3 (4194304 B fits)

  hipLaunchKernelGGL(tsum_kernel, dim3(NN), dim3(64), 0, stream, text, T);
  hipLaunchKernelGGL(convert_kernel, dim3(DD * DD / 1024, 1, 3), dim3(256), 0, stream,
                     text, visual, W3, th, tl, vh, vl, w3h, w3l);
  hipLaunchKernelGGL(transpose_kernel, dim3(DD / 32, DD / 32, 2), dim3(256), 0, stream,
                     W1, W2, w1th, w1tl, w2th, w2tl);
  hipLaunchKernelGGL(mfma1_kernel, dim3(DD / 64, NN / 64, 3), dim3(256), 0, stream,
                     th, tl, vh, vl, w1th, w1tl, w2th, w2tl, w3h, w3l,
                     Ah, Al, kw2t, kw3v);
  hipLaunchKernelGGL(mfma2_kernel, dim3(MM / 64, NN / 64, 4), dim3(256), 0, stream,
                     Ah, Al, vh, vl, Q);
  hipLaunchKernelGGL(main_kernel, dim3(MM / 32, NN / 16, 2), dim3(256), 0, stream,
                     text, kw2t, kw3v, Q, Spart);
  hipLaunchKernelGGL(combine_kernel, dim3(NN * MM / 1024), dim3(256), 0, stream,
                     Spart, T, out);
}